// Round 15
// baseline (427.688 us; speedup 1.0000x reference)
//
#include <hip/hip_runtime.h>
#include <hip/hip_bf16.h>
#include <hip/hip_fp16.h>

#define NN 2048
#define KK 8
#define DD 32
#define ZSZ (KK * NN * DD)   // 524288 floats
#define ZS2 (KK * NN * 16)   // 262144 u32 per partial chunk (fp16x2)
#define PSTR 20
#define NBLK 512
#define NCH 16
#define NS 4

typedef __attribute__((ext_vector_type(8))) short short8;
typedef __attribute__((ext_vector_type(4))) float f32x4;
typedef __attribute__((ext_vector_type(4))) unsigned int u32x4;
typedef unsigned long long u64;

union UU { u32x4 q; short8 v; unsigned int u[4]; };

#define SELHI 0x07060302u
#define SELLO 0x05040100u

__device__ __forceinline__ unsigned int prm(unsigned int a, unsigned int b, unsigned int sel) {
  return __builtin_amdgcn_perm(a, b, sel);
}
__device__ __forceinline__ unsigned int bfr(float x) {
  unsigned int u = __float_as_uint(x);
  return (u + 0x7fffu + ((u >> 16) & 1u)) >> 16;
}
__device__ __forceinline__ unsigned int packp(float a, float b) {
  union { __hip_bfloat162 h; unsigned int u; } cv;
  cv.h = __float22bfloat162_rn(make_float2(a, b));
  return cv.u;
}
__device__ __forceinline__ unsigned int packh(float a, float b) {
  union { __half2 h; unsigned int u; } cv;
  cv.h = __float22half2_rn(make_float2(a, b));
  return cv.u;
}
__device__ __forceinline__ float2 unpackh(unsigned int u) {
  union { unsigned int u; __half2 h; } cv;
  cv.u = u;
  return __half22float2(cv.h);
}
__device__ __forceinline__ f32x4 MF(short8 a, short8 b, f32x4 c) {
  return __builtin_amdgcn_mfma_f32_16x16x32_bf16(a, b, c, 0, 0, 0);
}
__device__ __forceinline__ short8 as_s8(u32x4 x) { UU u; u.q = x; return u.v; }

// ---- system-scope (sc0 sc1) accessors: bypass per-XCD L2, coherent at L3 ----
__device__ __forceinline__ uint2 ld2(const unsigned int* p) {
  u64 v = __hip_atomic_load((const u64*)p, __ATOMIC_RELAXED, __HIP_MEMORY_SCOPE_SYSTEM);
  return make_uint2((unsigned int)v, (unsigned int)(v >> 32));
}
__device__ __forceinline__ void st2(unsigned int* p, unsigned int a, unsigned int b) {
  __hip_atomic_store((u64*)p, (u64)a | ((u64)b << 32), __ATOMIC_RELAXED,
                     __HIP_MEMORY_SCOPE_SYSTEM);
}
__device__ __forceinline__ unsigned int ld1(const unsigned int* p) {
  return __hip_atomic_load(p, __ATOMIC_RELAXED, __HIP_MEMORY_SCOPE_SYSTEM);
}
__device__ __forceinline__ void st1(unsigned int* p, unsigned int v) {
  __hip_atomic_store(p, v, __ATOMIC_RELAXED, __HIP_MEMORY_SCOPE_SYSTEM);
}
__device__ __forceinline__ void st1s(unsigned short* p, unsigned short v) {
  __hip_atomic_store(p, v, __ATOMIC_RELAXED, __HIP_MEMORY_SCOPE_SYSTEM);
}
__device__ __forceinline__ float ld1f(const float* p) {
  return __uint_as_float(ld1((const unsigned int*)p));
}
__device__ __forceinline__ void st1f(float* p, float v) {
  st1((unsigned int*)p, __float_as_uint(v));
}
__device__ __forceinline__ u32x4 ld4(const unsigned int* p) {
  uint2 a = ld2(p), b = ld2(p + 2);
  u32x4 r = {a.x, a.y, b.x, b.y};
  return r;
}

// grid barrier: release-arrive + flag; intermediates are L2-bypassing so no
// cache maintenance of working data is needed (R8's 312 MB refetch bug).
__device__ __forceinline__ void gsync(unsigned int* bar, unsigned int ep) {
  __syncthreads();
  if (threadIdx.x == 0) {
    __hip_atomic_fetch_add(&bar[16 * ep], 1u, __ATOMIC_RELEASE, __HIP_MEMORY_SCOPE_SYSTEM);
    if (blockIdx.x == 0) {
      while (__hip_atomic_load(&bar[16 * ep], __ATOMIC_RELAXED, __HIP_MEMORY_SCOPE_SYSTEM) < NBLK)
        __builtin_amdgcn_s_sleep(16);
      (void)__hip_atomic_load(&bar[16 * ep], __ATOMIC_ACQUIRE, __HIP_MEMORY_SCOPE_SYSTEM);
      __hip_atomic_store(&bar[512], ep + 1u, __ATOMIC_RELEASE, __HIP_MEMORY_SCOPE_SYSTEM);
    } else {
      while (__hip_atomic_load(&bar[512], __ATOMIC_RELAXED, __HIP_MEMORY_SCOPE_SYSTEM) < ep + 1u)
        __builtin_amdgcn_s_sleep(16);
      (void)__hip_atomic_load(&bar[512], __ATOMIC_ACQUIRE, __HIP_MEMORY_SCOPE_SYSTEM);
    }
  }
  __syncthreads();
}

__global__ __launch_bounds__(256, 2) void fused_kernel(
    const int* __restrict__ adj, const float* __restrict__ feat,
    const float* __restrict__ W, const float* __restrict__ bias,
    float* Z0, float* Z1, unsigned short* Zghi, unsigned short* Zthi,
    unsigned int* mbits, unsigned int* partU, float* __restrict__ out,
    unsigned int* bar) {
  __shared__ __align__(16) unsigned int lds[8192 + 4 * 16 * PSTR];  // 37888 B
  const int t = threadIdx.x;
  const int bx = blockIdx.x;
  const int w = t >> 6;
  const int lane = t & 63;
  const int l15 = lane & 15;
  const int g = lane >> 4;

  // ============== phase P: proj+l2norm+pack (4 nodes/block) + mask ==============
  {
    const int nb = bx * 4;
    const int k = t >> 5, c = t & 31;
    float s[4];
#pragma unroll
    for (int j = 0; j < 4; ++j) s[j] = bias[k * DD + c];
    const float* wp = W + (k * 128) * DD + c;
    const float* fp = feat + nb * 128;  // uniform -> s_load
#pragma unroll 4
    for (int d = 0; d < 128; ++d) {
      float wv = wp[d * DD];
#pragma unroll
      for (int j = 0; j < 4; ++j) s[j] = fmaf(fp[j * 128 + d], wv, s[j]);
    }
    unsigned int hi[4];
#pragma unroll
    for (int j = 0; j < 4; ++j) {
      float sq = s[j] * s[j];
#pragma unroll
      for (int off = 16; off > 0; off >>= 1) sq += __shfl_xor(sq, off, 32);
      float z = s[j] / fmaxf(sqrtf(sq), 1e-12f);
      st1f(&Z0[(k * NN + nb + j) * DD + c], z);
      hi[j] = bfr(z);
      st1s(&Zghi[(k * NN + nb + j) * DD + c], (unsigned short)hi[j]);
    }
    st2((unsigned int*)&Zthi[(size_t)k * DD * NN + (size_t)c * NN + nb],
        hi[0] | (hi[1] << 16), hi[2] | (hi[3] << 16));
    // mask: 8192 ints/block
    for (int rr = 0; rr < 32; rr += 4) {
      int v[4];
#pragma unroll
      for (int j = 0; j < 4; ++j) v[j] = adj[bx * 8192 + (rr + j) * 256 + t];
#pragma unroll
      for (int j = 0; j < 4; ++j) {
        int idx = bx * 8192 + (rr + j) * 256 + t;
        unsigned long long bm = __ballot(v[j] > 0);
        if (lane == 0) st1(&mbits[idx >> 5], (unsigned int)bm);
        if (lane == 32) st1(&mbits[idx >> 5], (unsigned int)(bm >> 32));
      }
    }
  }
  unsigned int ep = 0;
  gsync(bar, ep++);

  float* zi = Z0;
  float* zo = Z1;

#pragma unroll 1
  for (int it = 0; it < 4; ++it) {
    // ============== phase I: gram + softmax(k) + aggregate ==============
    {
      const int nw = (bx & 31) * 64 + w * 16;
      const int mchunk = (bx >> 5) * (NS * 32);
      const unsigned int* Zg = (const unsigned int*)Zghi;
      const unsigned int* Zt = (const unsigned int*)Zthi;

      short8 A[KK];
#pragma unroll
      for (int k = 0; k < KK; ++k)
        A[k] = as_s8(ld4(&Zg[(size_t)(k * NN + nw + l15) * 16 + 4 * g]));

      f32x4 O[KK][2];
#pragma unroll
      for (int k = 0; k < KK; ++k)
#pragma unroll
        for (int ch = 0; ch < 2; ++ch) O[k][ch] = {0.0f, 0.0f, 0.0f, 0.0f};

      const int sqd = t & 3;
      const int sr0 = t >> 2;
      u32x4 Lgh[4], Lth[4];
      auto do_loads = [&](int mb) {
#pragma unroll
        for (int j = 0; j < 4; ++j) {
          int r = 64 * j + sr0;
          int k = r >> 5, rm = r & 31;
          Lgh[j] = ld4(&Zg[(size_t)k * (NN * 16) + (size_t)(mb + rm) * 16 + sqd * 4]);
          Lth[j] = ld4(&Zt[(size_t)k * (NN * 16) + (size_t)rm * (NN / 2) + (mb >> 1) + sqd * 4]);
        }
      };
      do_loads(mchunk);

      unsigned int* Pw = &lds[8192 + w * (16 * PSTR)];

#pragma unroll 1
      for (int st = 0; st < NS; ++st) {
        const int mb = mchunk + st * 32;
        __syncthreads();
#pragma unroll
        for (int j = 0; j < 4; ++j) {
          int r = 64 * j + sr0;
          *(u32x4*)&lds[r * 16 + 4 * sqd] = Lgh[j];
          *(u32x4*)&lds[4096 + r * 16 + 4 * sqd] = Lth[j];
        }
        __syncthreads();
        if (st + 1 < NS) do_loads(mb + 32);

        unsigned int mw[4];
#pragma unroll
        for (int r = 0; r < 4; ++r)
          mw[r] = ld1(&mbits[(size_t)(nw + 4 * g + r) * 64 + (mb >> 5)]);

        unsigned int pp[4][2][4];
#pragma unroll
        for (int sub = 0; sub < 2; ++sub) {
          f32x4 S[KK];
#pragma unroll
          for (int k = 0; k < KK; ++k) {
            int m = 16 * sub + l15;
            u32x4 bh = *(const u32x4*)&lds[(k * 32 + m) * 16 + 4 * g];
            f32x4 z = {0.0f, 0.0f, 0.0f, 0.0f};
            S[k] = MF(A[k], as_s8(bh), z);
          }
#pragma unroll
          for (int r = 0; r < 4; ++r) {
            float e[KK];
            float sum = 0.0f;
#pragma unroll
            for (int k = 0; k < KK; ++k) { e[k] = __expf(S[k][r]); sum += e[k]; }
            int ml = 16 * sub + l15;
            float f = ((mw[r] >> ml) & 1u) ? __builtin_amdgcn_rcpf(sum) : 0.0f;
#pragma unroll
            for (int k = 0; k < KK; ++k) S[k][r] = e[k] * f;
#pragma unroll
            for (int kp = 0; kp < 4; ++kp)
              pp[kp][sub][r] = packp(S[2 * kp][r], S[2 * kp + 1][r]);
          }
        }

#pragma unroll
        for (int kp = 0; kp < 4; ++kp) {
#pragma unroll
          for (int sub = 0; sub < 2; ++sub)
#pragma unroll
            for (int r = 0; r < 4; ++r)
              Pw[(4 * g + r) * PSTR + 16 * sub + l15] = pp[kp][sub][r];

          const unsigned int* Pr = &Pw[l15 * PSTR + 8 * g];
          u32x4 a0 = *(const u32x4*)Pr;
          u32x4 a1 = *(const u32x4*)(Pr + 4);
          UU pk0, pk1;
          pk0.u[0] = prm(a0.y, a0.x, SELLO); pk0.u[1] = prm(a0.w, a0.z, SELLO);
          pk0.u[2] = prm(a1.y, a1.x, SELLO); pk0.u[3] = prm(a1.w, a1.z, SELLO);
          pk1.u[0] = prm(a0.y, a0.x, SELHI); pk1.u[1] = prm(a0.w, a0.z, SELHI);
          pk1.u[2] = prm(a1.y, a1.x, SELHI); pk1.u[3] = prm(a1.w, a1.z, SELHI);
#pragma unroll
          for (int kk = 0; kk < 2; ++kk) {
            int k = 2 * kp + kk;
#pragma unroll
            for (int ch = 0; ch < 2; ++ch) {
              int c = 16 * ch + l15;
              u32x4 b = *(const u32x4*)&lds[4096 + (k * 32 + c) * 16 + 4 * g];
              O[k][ch] = MF(kk ? pk1.v : pk0.v, as_s8(b), O[k][ch]);
            }
          }
        }
      }

      unsigned int* dst = partU + (size_t)(bx >> 5) * ZS2;
      const int even = ((l15 & 1) == 0);
#pragma unroll
      for (int k = 0; k < KK; ++k)
#pragma unroll
        for (int ch = 0; ch < 2; ++ch) {
          f32x4 o = O[k][ch];
#pragma unroll
          for (int r = 0; r < 4; ++r) {
            float partner = __shfl_xor(o[r], 1);
            if (even)
              st1(&dst[(size_t)(k * NN + nw + 4 * g + r) * 16 + ((16 * ch + l15) >> 1)],
                  packh(o[r], partner));
          }
        }
    }
    gsync(bar, ep++);

    if (it < 3) {
      // ============== phase R: reduce + l2norm + repack ==============
      {
        unsigned short(*T)[33] = (unsigned short(*)[33])lds;
        const int k = bx >> 6, mt = bx & 63;
        const int m0 = mt * 32;
        const int mloc = t >> 3, c4 = t & 7;
        const size_t idx = (size_t)(k * NN + m0 + mloc) * DD + 4 * c4;
        uint2 va = ld2((const unsigned int*)&zi[idx]);
        uint2 vb = ld2((const unsigned int*)&zi[idx + 2]);
        float4 v = make_float4(__uint_as_float(va.x), __uint_as_float(va.y),
                               __uint_as_float(vb.x), __uint_as_float(vb.y));
#pragma unroll
        for (int j = 0; j < NCH; ++j) {
          uint2 pq = ld2(&partU[(size_t)j * ZS2 + (size_t)(k * NN + m0 + mloc) * 16 + 2 * c4]);
          float2 f0 = unpackh(pq.x), f1 = unpackh(pq.y);
          v.x += f0.x; v.y += f0.y; v.z += f1.x; v.w += f1.y;
        }
        float sq = v.x * v.x + v.y * v.y + v.z * v.z + v.w * v.w;
        sq += __shfl_xor(sq, 1, 8);
        sq += __shfl_xor(sq, 2, 8);
        sq += __shfl_xor(sq, 4, 8);
        const float sc = 1.0f / fmaxf(sqrtf(sq), 1e-12f);
        float z[4] = {v.x * sc, v.y * sc, v.z * sc, v.w * sc};
        st2((unsigned int*)&zo[idx], __float_as_uint(z[0]), __float_as_uint(z[1]));
        st2((unsigned int*)&zo[idx + 2], __float_as_uint(z[2]), __float_as_uint(z[3]));
        unsigned int hi[4];
#pragma unroll
        for (int e = 0; e < 4; ++e) {
          hi[e] = bfr(z[e]);
          T[4 * c4 + e][mloc] = (unsigned short)hi[e];
        }
        st2((unsigned int*)&Zghi[idx], hi[0] | (hi[1] << 16), hi[2] | (hi[3] << 16));
        __syncthreads();
        const int cloc = t >> 3, m4 = t & 7;
        unsigned int o0 = (unsigned int)T[cloc][4 * m4 + 0] | ((unsigned int)T[cloc][4 * m4 + 1] << 16);
        unsigned int o1 = (unsigned int)T[cloc][4 * m4 + 2] | ((unsigned int)T[cloc][4 * m4 + 3] << 16);
        st2((unsigned int*)&Zthi[(size_t)k * DD * NN + (size_t)cloc * NN + m0 + 4 * m4], o0, o1);
        __syncthreads();  // LDS safe for next phase
      }
      gsync(bar, ep++);
      float* tz = zi; zi = zo; zo = tz;
    } else {
      // ============== phase RO: reduce + l2norm + output ==============
      const int k = t >> 5, c = t & 31;
#pragma unroll
      for (int j = 0; j < 4; ++j) {
        const int n = bx * 4 + j;
        const size_t idx = (size_t)(k * NN + n) * DD + c;
        float v = ld1f(&zi[idx]);
#pragma unroll
        for (int q = 0; q < NCH; ++q) {
          unsigned int pu = ld1(&partU[(size_t)q * ZS2 + (size_t)(k * NN + n) * 16 + (c >> 1)]);
          float2 f = unpackh(pu);
          v += (c & 1) ? f.y : f.x;
        }
        float sq = v * v;
#pragma unroll
        for (int off = 16; off > 0; off >>= 1) sq += __shfl_xor(sq, off, 32);
        out[n * (KK * DD) + t] = v / fmaxf(sqrtf(sq), 1e-12f);
      }
    }
  }
}

extern "C" void kernel_launch(void* const* d_in, const int* in_sizes, int n_in,
                              void* d_out, int out_size, void* d_ws, size_t ws_size,
                              hipStream_t stream) {
  const int* adj = (const int*)d_in[0];
  const float* feat = (const float*)d_in[1];
  const float* W = (const float*)d_in[2];
  const float* b = (const float*)d_in[3];
  float* out = (float*)d_out;

  unsigned int* bar = (unsigned int*)d_ws;  // 4 KB
  float* Z0 = (float*)((char*)d_ws + 4096);
  float* Z1 = Z0 + ZSZ;
  unsigned short* Zghi = (unsigned short*)(Z1 + ZSZ);
  unsigned short* Zthi = Zghi + ZSZ;
  unsigned int* mbits = (unsigned int*)(Zthi + ZSZ);
  unsigned int* partU = mbits + NN * 64;  // 16 MB

  hipMemsetAsync(bar, 0, 4096, stream);
  fused_kernel<<<NBLK, 256, 0, stream>>>(adj, feat, W, b, Z0, Z1, Zghi, Zthi,
                                         mbits, partU, out, bar);
}